// Round 1
// baseline (361.047 us; speedup 1.0000x reference)
//
#include <hip/hip_runtime.h>
#include <math.h>

// ---------------------------------------------------------------------------
// QuantumPoolingLayer: pooled quadrant means -> tanh angles -> 4-qubit circuit
// inputs:  (128, 32, 32, 512) f32   [b][i][j][m], m contiguous
// weights: (512, 2, 4, 3) f32       [m][layer][k][{phi,theta,omega}]
// out:     (128, 512) f32           z = <Z_0>
// ---------------------------------------------------------------------------

#define B_DIM   128
#define N_DIM   32
#define M_DIM   512
#define PI_F    3.14159265358979323846f

// ============================ Kernel 1: pooling ============================
// grid = 128 b * 2 qi * 4 chunks = 1024 blocks; block = 256 threads.
// thread t: m4 = t&127 (float4 channel group), joff = t>>7 (which of 2 j cols).
// Each block sums 4 rows x 32 cols, split into qj=0 (j<16) / qj=1 (j>=16).
// Partials written to ws: float4 layout [b][qi][chunk][qj][m4].
__global__ __launch_bounds__(256)
void pool_kernel(const float* __restrict__ in, float* __restrict__ ws) {
    int blk   = blockIdx.x;
    int chunk = blk & 3;
    int qi    = (blk >> 2) & 1;
    int b     = blk >> 3;
    int t     = threadIdx.x;
    int m4    = t & 127;
    int joff  = t >> 7;
    int i0    = qi * 16 + chunk * 4;

    const float4* in4 = (const float4*)in + (size_t)b * (N_DIM * N_DIM * (M_DIM / 4));

    float4 a0 = make_float4(0.f, 0.f, 0.f, 0.f);
    float4 a1 = make_float4(0.f, 0.f, 0.f, 0.f);

    for (int r = 0; r < 4; ++r) {
        int i = i0 + r;
        const float4* row = in4 + (size_t)i * (N_DIM * (M_DIM / 4));
        #pragma unroll
        for (int jp = 0; jp < 16; ++jp) {
            int j = jp * 2 + joff;
            float4 v = row[(j << 7) + m4];
            if (jp < 8) { a0.x += v.x; a0.y += v.y; a0.z += v.z; a0.w += v.w; }
            else        { a1.x += v.x; a1.y += v.y; a1.z += v.z; a1.w += v.w; }
        }
    }

    // combine the two joff halves via LDS
    __shared__ float4 red[2][128];
    if (joff) { red[0][m4] = a0; red[1][m4] = a1; }
    __syncthreads();
    if (!joff) {
        float4 r0 = red[0][m4], r1 = red[1][m4];
        a0.x += r0.x; a0.y += r0.y; a0.z += r0.z; a0.w += r0.w;
        a1.x += r1.x; a1.y += r1.y; a1.z += r1.z; a1.w += r1.w;
        float4* w4 = (float4*)ws;
        size_t base = ((size_t)((b * 2 + qi) * 4 + chunk) * 2) * 128 + m4;
        w4[base]       = a0;   // qj = 0
        w4[base + 128] = a1;   // qj = 1
    }
}

// ========================= Kernel 2: quantum sim ===========================
struct Cpx { float x, y; };

// apply 2x2 complex gate on wire with mask M (wire w -> mask 8>>w)
template<int M>
__device__ __forceinline__ void apply1q(float* re, float* im,
                                        Cpx g00, Cpx g01, Cpx g10, Cpx g11) {
    #pragma unroll
    for (int s = 0; s < 16; ++s) {
        if (s & M) continue;
        int s1 = s | M;
        float ar = re[s],  ai = im[s];
        float br = re[s1], bi = im[s1];
        re[s]  = g00.x * ar - g00.y * ai + g01.x * br - g01.y * bi;
        im[s]  = g00.x * ai + g00.y * ar + g01.x * bi + g01.y * br;
        re[s1] = g10.x * ar - g10.y * ai + g11.x * br - g11.y * bi;
        im[s1] = g10.x * ai + g10.y * ar + g11.x * bi + g11.y * br;
    }
}

template<int MC, int MT>
__device__ __forceinline__ void cnot(float* re, float* im) {
    #pragma unroll
    for (int s = 0; s < 16; ++s) {
        if ((s & MC) && !(s & MT)) {
            int s1 = s | MT;
            float t;
            t = re[s]; re[s] = re[s1]; re[s1] = t;
            t = im[s]; im[s] = im[s1]; im[s1] = t;
        }
    }
}

__device__ __forceinline__ void rot_gate(float phi, float theta, float omega,
                                         Cpx& g00, Cpx& g01, Cpx& g10, Cpx& g11) {
    float st, ct, sa, ca, sd, cd;
    __sincosf(0.5f * theta, &st, &ct);
    __sincosf(0.5f * (phi + omega), &sa, &ca);
    __sincosf(0.5f * (phi - omega), &sd, &cd);
    // g00 = e^{-i(phi+omega)/2} ct ; g01 = -e^{+i(phi-omega)/2} st
    // g10 = e^{-i(phi-omega)/2} st ; g11 = e^{+i(phi+omega)/2} ct
    g00.x =  ca * ct;  g00.y = -sa * ct;
    g01.x = -cd * st;  g01.y = -sd * st;
    g10.x =  cd * st;  g10.y = -sd * st;
    g11.x =  ca * ct;  g11.y =  sa * ct;
}

__global__ __launch_bounds__(256)
void quantum_kernel(const float* __restrict__ ws, const float* __restrict__ qw,
                    float* __restrict__ out) {
    int idx = blockIdx.x * 256 + threadIdx.x;   // 65536 threads
    int m = idx & (M_DIM - 1);
    int b = idx >> 9;

    // pooled[qi*2+qj] = (sum over 4 chunk-partials) / 256
    float ang[4];
    #pragma unroll
    for (int qi = 0; qi < 2; ++qi) {
        #pragma unroll
        for (int qj = 0; qj < 2; ++qj) {
            float s = 0.f;
            #pragma unroll
            for (int c = 0; c < 4; ++c) {
                s += ws[((size_t)((b * 2 + qi) * 4 + c) * 2 + qj) * M_DIM + m];
            }
            ang[qi * 2 + qj] = tanhf(s * (1.0f / 256.0f)) * PI_F;
        }
    }

    // state after RY(ang[k]) on wire k applied to |0000>: real product state
    float cs[4], sn[4];
    #pragma unroll
    for (int k = 0; k < 4; ++k) __sincosf(0.5f * ang[k], &sn[k], &cs[k]);

    float re[16], im[16];
    #pragma unroll
    for (int s = 0; s < 16; ++s) {
        re[s] = ((s & 8) ? sn[0] : cs[0]) * ((s & 4) ? sn[1] : cs[1]) *
                ((s & 2) ? sn[2] : cs[2]) * ((s & 1) ? sn[3] : cs[3]);
        im[s] = 0.f;
    }

    const float* wbase = qw + (size_t)m * 24;   // [m][layer][k][3]
    #pragma unroll
    for (int layer = 0; layer < 2; ++layer) {
        const float* wl = wbase + layer * 12;
        Cpx g00, g01, g10, g11;
        rot_gate(wl[0],  wl[1],  wl[2],  g00, g01, g10, g11); apply1q<8>(re, im, g00, g01, g10, g11);
        rot_gate(wl[3],  wl[4],  wl[5],  g00, g01, g10, g11); apply1q<4>(re, im, g00, g01, g10, g11);
        rot_gate(wl[6],  wl[7],  wl[8],  g00, g01, g10, g11); apply1q<2>(re, im, g00, g01, g10, g11);
        rot_gate(wl[9],  wl[10], wl[11], g00, g01, g10, g11); apply1q<1>(re, im, g00, g01, g10, g11);
        // CNOTs: (0,1) (0,2) (0,3) (1,2) (1,3) (2,3); wire w -> mask 8>>w
        cnot<8, 4>(re, im);
        cnot<8, 2>(re, im);
        cnot<8, 1>(re, im);
        cnot<4, 2>(re, im);
        cnot<4, 1>(re, im);
        cnot<2, 1>(re, im);
    }

    float z = 0.f;
    #pragma unroll
    for (int s = 0; s < 16; ++s) {
        float p = re[s] * re[s] + im[s] * im[s];
        z += (s & 8) ? -p : p;
    }
    out[idx] = z;
}

// ================================ launch ===================================
extern "C" void kernel_launch(void* const* d_in, const int* in_sizes, int n_in,
                              void* d_out, int out_size, void* d_ws, size_t ws_size,
                              hipStream_t stream) {
    const float* in = (const float*)d_in[0];   // (128,32,32,512) f32
    const float* qw = (const float*)d_in[1];   // (512,2,4,3) f32
    float* out = (float*)d_out;                // (128,512) f32
    float* ws  = (float*)d_ws;                 // needs 4 MiB of partials

    (void)in_sizes; (void)n_in; (void)out_size; (void)ws_size;

    pool_kernel<<<B_DIM * 2 * 4, 256, 0, stream>>>(in, ws);
    quantum_kernel<<<(B_DIM * M_DIM) / 256, 256, 0, stream>>>(ws, qw, out);
}